// Round 7
// baseline (575.787 us; speedup 1.0000x reference)
//
#include <hip/hip_runtime.h>
#include <hip/hip_bf16.h>

#define HID    128
#define FPITCH 136   // fallback-kernel pitch (>= HID, padded)
#define TPB    256

typedef __attribute__((ext_vector_type(8))) __bf16 bf16x8;
typedef __attribute__((ext_vector_type(4))) __bf16 bf16x4;
typedef __attribute__((ext_vector_type(4))) float  f32x4;

// --- pre-kernel: block 0 builds w1t = W1^T in bf16, CHUNK-SWIZZLED layout:
//     element (n, chunk c) at n*128 + ((c+n)&15)*8   (c = k0/8, 16 chunks/row)
//     all blocks grid-stride cast x fp32 -> xb bf16 (fully coalesced) ---
__global__ __launch_bounds__(TPB) void prep_kernel(
    const float* __restrict__ W1, __bf16* __restrict__ w1t,
    const float* __restrict__ x, __bf16* __restrict__ xb, int n_x4) {
  if (xb) {
    for (int i = blockIdx.x * TPB + threadIdx.x; i < n_x4; i += gridDim.x * TPB) {
      float4 a = reinterpret_cast<const float4*>(x)[i];
      bf16x4 v;
      v[0] = (__bf16)a.x; v[1] = (__bf16)a.y; v[2] = (__bf16)a.z; v[3] = (__bf16)a.w;
      reinterpret_cast<bf16x4*>(xb)[i] = v;
    }
  }
  if (blockIdx.x == 0 && w1t) {
    __shared__ float w[HID * HID];
    for (int i = threadIdx.x; i < HID * HID; i += TPB) w[i] = W1[i];
    __syncthreads();
    for (int s = threadIdx.x; s < HID * (HID / 8); s += TPB) {
      int n = s >> 4;          // output row (W1 column)
      int c = s & 15;          // logical k-chunk
      bf16x8 v;
#pragma unroll
      for (int j = 0; j < 8; ++j) v[j] = (__bf16)w[(c * 8 + j) * HID + n];
      *reinterpret_cast<bf16x8*>(&w1t[n * HID + ((c + n) & 15) * 8]) = v;
    }
  }
}

// 16x16x32 MFMA decode: 16 edges/wave, quad-coalesced gathers (R3 structure).
// Round 7 occupancy play, corrected: sW = 32768B swizzled (PITCH=128 full rows
// — R6's PITCH=120 truncated rows: PITCH >= HID is a correctness invariant);
// b1/W2 live in 16 per-lane registers (n === m mod 16) so LDS block = 32768B
// -> 5 blocks/CU; __launch_bounds__(256,5) caps VGPR at 102 (est. ~90).
__global__ __launch_bounds__(TPB, 5) void vgae_decode_kernel(
    const __bf16* __restrict__ xb,
    const __bf16* __restrict__ w1t,
    const float* __restrict__ b1,
    const float* __restrict__ W2,
    const float* __restrict__ b2,
    const int* __restrict__ eip,
    const int* __restrict__ ein,
    float* __restrict__ out,
    int E, int n_tiles)
{
  __shared__ __bf16 sW[HID * HID];   // 32768 B exactly (swizzled layout)

  {  // linear 16B copy from w1t (swizzle baked in)
    const uint4* srcp = reinterpret_cast<const uint4*>(w1t);
    uint4*       dstp = reinterpret_cast<uint4*>(sW);
    for (int i = threadIdx.x; i < (HID * HID) / 8; i += TPB) dstp[i] = srcp[i];
  }

  const int lane = threadIdx.x & 63;
  const int wave = threadIdx.x >> 6;
  const int m    = lane & 15;   // edge-within-wave (A row) / n-within-tile (B col)
  const int quad = lane >> 4;   // k-chunk select; C row group
  const float b2v = b2[0];

  // per-lane bias/W2 registers: this lane only touches n = nt*16 + m
  float rb1[8], rw2[8];
#pragma unroll
  for (int nt = 0; nt < 8; ++nt) {
    rb1[nt] = b1[nt * 16 + m];
    rw2[nt] = W2[nt * 16 + m];
  }

  __syncthreads();

  // prefetch first tile's indices
  int tile = blockIdx.x;
  int nsrc = 0, ndst = 0;
  if (tile < n_tiles) {
    const int e_base = tile * 64 + wave * 16;
    const int* ei = (e_base < E) ? eip : ein;
    const int  eo = (e_base < E) ? e_base : (e_base - E);
    nsrc = ei[eo + m];
    ndst = ei[E + eo + m];
  }

  for (; tile < n_tiles; tile += gridDim.x) {
    const __bf16* xs = xb + (size_t)nsrc * HID;
    const __bf16* xd = xb + (size_t)ndst * HID;

    // issue all 8 row-chunk loads back-to-back (max MLP), then convert —
    // S/D die before acc is allocated (keeps peak VGPR low).
    bf16x8 a[4];
    {
      bf16x8 S[4], D[4];
#pragma unroll
      for (int kt = 0; kt < 4; ++kt) {
        const int k0 = kt * 32 + quad * 8;
        S[kt] = *reinterpret_cast<const bf16x8*>(xs + k0);
        D[kt] = *reinterpret_cast<const bf16x8*>(xd + k0);
      }
#pragma unroll
      for (int kt = 0; kt < 4; ++kt) {
#pragma unroll
        for (int j = 0; j < 8; ++j) {
          float p = (float)S[kt][j] * (float)D[kt][j];
          a[kt][j] = (__bf16)fmaxf(p, 0.f);
        }
      }
    }

    // prefetch next tile's indices (hides idx-load latency)
    const int tn = tile + gridDim.x;
    if (tn < n_tiles) {
      const int e2 = tn * 64 + wave * 16;
      const int* ei2 = (e2 < E) ? eip : ein;
      const int  eo2 = (e2 < E) ? e2 : (e2 - E);
      nsrc = ei2[eo2 + m];
      ndst = ei2[E + eo2 + m];
    }

    // MFMA sweep over W1. Swizzled B-row read: chunk (kt*4+quad) of row n
    // lives at n*128 + ((kt*4+quad+n)&15)*8 ; n = nt*16+m -> n&15 == m.
    f32x4 acc[8] = {};
#pragma unroll
    for (int kt = 0; kt < 4; ++kt) {
#pragma unroll
      for (int nt = 0; nt < 8; ++nt) {
        const int n = nt * 16 + m;
        bf16x8 bfr = *reinterpret_cast<const bf16x8*>(
            &sW[n * HID + ((kt * 4 + quad + m) & 15) * 8]);
        acc[nt] = __builtin_amdgcn_mfma_f32_16x16x32_bf16(a[kt], bfr, acc[nt], 0, 0, 0);
      }
    }

    // epilogue: p[r] = sum_n relu(C[row][n]+b1[n])*W2[n]
    float p[4] = {0.f, 0.f, 0.f, 0.f};
#pragma unroll
    for (int nt = 0; nt < 8; ++nt) {
      const float b1n = rb1[nt];
      const float w2n = rw2[nt];
#pragma unroll
      for (int r = 0; r < 4; ++r) {
        float t = fmaxf(acc[nt][r] + b1n, 0.f);
        p[r] = fmaf(t, w2n, p[r]);
      }
    }
#pragma unroll
    for (int off = 1; off < 16; off <<= 1) {
#pragma unroll
      for (int r = 0; r < 4; ++r) p[r] += __shfl_xor(p[r], off, 64);
    }
    if (m == 0) {
      float4 o;
      o.x = 1.f / (1.f + __expf(-(p[0] + b2v)));
      o.y = 1.f / (1.f + __expf(-(p[1] + b2v)));
      o.z = 1.f / (1.f + __expf(-(p[2] + b2v)));
      o.w = 1.f / (1.f + __expf(-(p[3] + b2v)));
      *reinterpret_cast<float4*>(out + tile * 64 + wave * 16 + quad * 4) = o;
    }
  }
}

// fp32 fallback (ws too small for xb) — own padded-pitch LDS layout
__global__ __launch_bounds__(TPB) void vgae_decode_fallback(
    const float* __restrict__ x,
    const float* __restrict__ W1,
    const float* __restrict__ b1,
    const float* __restrict__ W2,
    const float* __restrict__ b2,
    const int* __restrict__ eip,
    const int* __restrict__ ein,
    float* __restrict__ out,
    int E, int n_tiles)
{
  __shared__ __bf16 sW[HID * FPITCH];
  __shared__ float  sb1[HID];
  __shared__ float  sw2[HID];
  for (int c = threadIdx.x; c < HID * (HID / 8); c += TPB) {
    int n = c >> 4, k0 = (c & 15) << 3;
    bf16x8 v;
#pragma unroll
    for (int j = 0; j < 8; ++j) v[j] = (__bf16)W1[(k0 + j) * HID + n];
    *reinterpret_cast<bf16x8*>(&sW[n * FPITCH + k0]) = v;
  }
  if (threadIdx.x < HID) { sb1[threadIdx.x] = b1[threadIdx.x]; sw2[threadIdx.x] = W2[threadIdx.x]; }
  __syncthreads();
  const int lane = threadIdx.x & 63, wave = threadIdx.x >> 6;
  const int m = lane & 15, quad = lane >> 4;
  const float b2v = b2[0];
  for (int tile = blockIdx.x; tile < n_tiles; tile += gridDim.x) {
    const int e_base = tile * 64 + wave * 16;
    const int* ei = (e_base < E) ? eip : ein;
    const int  eo = (e_base < E) ? e_base : (e_base - E);
    const int src = ei[eo + m], dst = ei[E + eo + m];
    const float* xs = x + (size_t)src * HID;
    const float* xd = x + (size_t)dst * HID;
    f32x4 acc[8] = {};
#pragma unroll
    for (int kt = 0; kt < 4; ++kt) {
      const int k0 = kt * 32 + quad * 8;
      float4 s0 = *reinterpret_cast<const float4*>(xs + k0);
      float4 s1 = *reinterpret_cast<const float4*>(xs + k0 + 4);
      float4 d0 = *reinterpret_cast<const float4*>(xd + k0);
      float4 d1 = *reinterpret_cast<const float4*>(xd + k0 + 4);
      bf16x8 a;
      a[0] = (__bf16)fmaxf(s0.x * d0.x, 0.f); a[1] = (__bf16)fmaxf(s0.y * d0.y, 0.f);
      a[2] = (__bf16)fmaxf(s0.z * d0.z, 0.f); a[3] = (__bf16)fmaxf(s0.w * d0.w, 0.f);
      a[4] = (__bf16)fmaxf(s1.x * d1.x, 0.f); a[5] = (__bf16)fmaxf(s1.y * d1.y, 0.f);
      a[6] = (__bf16)fmaxf(s1.z * d1.z, 0.f); a[7] = (__bf16)fmaxf(s1.w * d1.w, 0.f);
#pragma unroll
      for (int nt = 0; nt < 8; ++nt) {
        bf16x8 bfr = *reinterpret_cast<const bf16x8*>(&sW[(nt * 16 + m) * FPITCH + k0]);
        acc[nt] = __builtin_amdgcn_mfma_f32_16x16x32_bf16(a, bfr, acc[nt], 0, 0, 0);
      }
    }
    float p[4] = {0.f, 0.f, 0.f, 0.f};
#pragma unroll
    for (int nt = 0; nt < 8; ++nt) {
      const int n = nt * 16 + m;
      const float b1n = sb1[n], w2n = sw2[n];
#pragma unroll
      for (int r = 0; r < 4; ++r) p[r] = fmaf(fmaxf(acc[nt][r] + b1n, 0.f), w2n, p[r]);
    }
#pragma unroll
    for (int off = 1; off < 16; off <<= 1)
#pragma unroll
      for (int r = 0; r < 4; ++r) p[r] += __shfl_xor(p[r], off, 64);
    if (m == 0) {
      float4 o;
      o.x = 1.f / (1.f + __expf(-(p[0] + b2v)));
      o.y = 1.f / (1.f + __expf(-(p[1] + b2v)));
      o.z = 1.f / (1.f + __expf(-(p[2] + b2v)));
      o.w = 1.f / (1.f + __expf(-(p[3] + b2v)));
      *reinterpret_cast<float4*>(out + tile * 64 + wave * 16 + quad * 4) = o;
    }
  }
}

extern "C" void kernel_launch(void* const* d_in, const int* in_sizes, int n_in,
                              void* d_out, int out_size, void* d_ws, size_t ws_size,
                              hipStream_t stream) {
  const float* x  = (const float*)d_in[0];
  const float* W1 = (const float*)d_in[1];
  const float* b1 = (const float*)d_in[2];
  const float* W2 = (const float*)d_in[3];
  const float* b2 = (const float*)d_in[4];
  const int*  eip = (const int*)d_in[5];
  const int*  ein = (const int*)d_in[6];
  float* out = (float*)d_out;
  const int E = in_sizes[5] / 2;
  const int n_tiles = (2 * E) / 64;
  const int n_nodes = in_sizes[0] / HID;
  const int n_x4 = in_sizes[0] / 4;

  const size_t w1t_bytes = (size_t)HID * HID * sizeof(__bf16);
  const size_t xb_off    = 65536;
  const size_t xb_bytes  = (size_t)n_nodes * HID * sizeof(__bf16);

  __bf16* w1t = nullptr;
  __bf16* xb  = nullptr;
  if (ws_size >= w1t_bytes) w1t = (__bf16*)d_ws;
  if (ws_size >= xb_off + xb_bytes) xb = (__bf16*)((char*)d_ws + xb_off);

  if (w1t && xb) {
    int prep_grid = (n_x4 + TPB - 1) / TPB;
    if (prep_grid > 6400) prep_grid = 6400;
    prep_kernel<<<prep_grid, TPB, 0, stream>>>(W1, w1t, x, xb, n_x4);
    // 2500 blocks: n_tiles=20000 -> exactly 8 tiles per block (no tail imbalance)
    int grid = 2500;
    if (grid > n_tiles) grid = n_tiles;
    vgae_decode_kernel<<<grid, TPB, 0, stream>>>(xb, w1t, b1, W2, b2,
                                                 eip, ein, out, E, n_tiles);
  } else {
    vgae_decode_fallback<<<2560, TPB, 0, stream>>>(x, W1, b1, W2, b2,
                                                   eip, ein, out, E, n_tiles);
  }
}

// Round 8
// 501.602 us; speedup vs baseline: 1.1479x; 1.1479x over previous
//
#include <hip/hip_runtime.h>
#include <hip/hip_bf16.h>

#define HID   128
#define PITCH 136   // bf16/row; >=HID (correctness invariant!); 0 conflicts measured
#define TPB   256

typedef __attribute__((ext_vector_type(8))) __bf16 bf16x8;
typedef __attribute__((ext_vector_type(4))) __bf16 bf16x4;
typedef __attribute__((ext_vector_type(4))) float  f32x4;

// --- pre-kernel: block 0 transposes W1 -> w1t [n][PITCH] bf16 (k-contig);
//     all blocks grid-stride cast x fp32 -> xb bf16 (fully coalesced) ---
__global__ __launch_bounds__(TPB) void prep_kernel(
    const float* __restrict__ W1, __bf16* __restrict__ w1t,
    const float* __restrict__ x, __bf16* __restrict__ xb, int n_x4) {
  if (xb) {
    for (int i = blockIdx.x * TPB + threadIdx.x; i < n_x4; i += gridDim.x * TPB) {
      float4 a = reinterpret_cast<const float4*>(x)[i];
      bf16x4 v;
      v[0] = (__bf16)a.x; v[1] = (__bf16)a.y; v[2] = (__bf16)a.z; v[3] = (__bf16)a.w;
      reinterpret_cast<bf16x4*>(xb)[i] = v;
    }
  }
  if (blockIdx.x == 0 && w1t) {
    __shared__ float w[HID * HID];
    for (int i = threadIdx.x; i < HID * HID; i += TPB) w[i] = W1[i];
    __syncthreads();
    for (int c = threadIdx.x; c < HID * (HID / 8); c += TPB) {
      int n  = c >> 4;
      int k0 = (c & 15) << 3;
      bf16x8 v;
#pragma unroll
      for (int j = 0; j < 8; ++j) v[j] = (__bf16)w[(k0 + j) * HID + n];
      *reinterpret_cast<bf16x8*>(&w1t[n * PITCH + k0]) = v;
    }
  }
}

// 16x16x32 MFMA decode, R3 structure + PAIRWISE tiles:
// loads A -> convert A (stall) -> loads B (same S/D regs) -> MFMA+epi A
// (B lands underneath) -> convert B (no stall) -> MFMA+epi B.
// No pending-load register crosses an iteration (R5 spill trigger) and
// peak VGPR ~105 (R4 occupancy trigger at >128). launch_bounds(256,4)=cap 128.
__global__ __launch_bounds__(TPB, 4) void vgae_decode_kernel(
    const __bf16* __restrict__ xb,
    const __bf16* __restrict__ w1t,
    const float* __restrict__ b1,
    const float* __restrict__ W2,
    const float* __restrict__ b2,
    const int* __restrict__ eip,
    const int* __restrict__ ein,
    float* __restrict__ out,
    int E, int n_tiles)
{
  __shared__ __bf16 sW[HID * PITCH];   // 34816 B
  __shared__ float  sb1[HID];
  __shared__ float  sw2[HID];

  {  // linear 16B copy from w1t (layouts identical)
    const uint4* srcp = reinterpret_cast<const uint4*>(w1t);
    uint4*       dstp = reinterpret_cast<uint4*>(sW);
    for (int i = threadIdx.x; i < (HID * PITCH) / 8; i += TPB) dstp[i] = srcp[i];
  }
  if (threadIdx.x < HID) {
    sb1[threadIdx.x] = b1[threadIdx.x];
    sw2[threadIdx.x] = W2[threadIdx.x];
  }
  __syncthreads();

  const int lane = threadIdx.x & 63;
  const int wave = threadIdx.x >> 6;
  const int m    = lane & 15;   // edge-within-wave (A row) / n-within-tile (B col)
  const int quad = lane >> 4;   // k-chunk select; C row group
  const float b2v = b2[0];
  const int n_pairs = n_tiles >> 1;   // n_tiles = E/32 is even for E%64==0

  // prefetch first pair's indices (tiles 2p, 2p+1)
  int pair = blockIdx.x;
  int sA = 0, dA = 0, sB = 0, dB = 0;
  if (pair < n_pairs) {
    const int eb = pair * 128 + wave * 16;          // tile A base
    const int* eiA = (eb < E) ? eip : ein;
    const int  eoA = (eb < E) ? eb : (eb - E);
    sA = eiA[eoA + m];           dA = eiA[E + eoA + m];
    const int eb2 = eb + 64;                         // tile B base
    const int* eiB = (eb2 < E) ? eip : ein;
    const int  eoB = (eb2 < E) ? eb2 : (eb2 - E);
    sB = eiB[eoB + m];           dB = eiB[E + eoB + m];
  }

  for (; pair < n_pairs; pair += gridDim.x) {
    const int tileA = 2 * pair;
    const __bf16* xsA = xb + (size_t)sA * HID;
    const __bf16* xdA = xb + (size_t)dA * HID;
    const __bf16* xsB = xb + (size_t)sB * HID;
    const __bf16* xdB = xb + (size_t)dB * HID;

    bf16x8 S[4], D[4];
    // ---- loads A (8 x 16B, max MLP) ----
#pragma unroll
    for (int kt = 0; kt < 4; ++kt) {
      const int k0 = kt * 32 + quad * 8;
      S[kt] = *reinterpret_cast<const bf16x8*>(xsA + k0);
      D[kt] = *reinterpret_cast<const bf16x8*>(xdA + k0);
    }

    // ---- prefetch next pair's indices (ptrs already captured above) ----
    const int np = pair + gridDim.x;
    if (np < n_pairs) {
      const int eb = np * 128 + wave * 16;
      const int* eiA = (eb < E) ? eip : ein;
      const int  eoA = (eb < E) ? eb : (eb - E);
      sA = eiA[eoA + m];           dA = eiA[E + eoA + m];
      const int eb2 = eb + 64;
      const int* eiB = (eb2 < E) ? eip : ein;
      const int  eoB = (eb2 < E) ? eb2 : (eb2 - E);
      sB = eiB[eoB + m];           dB = eiB[E + eoB + m];
    }

    // ---- convert A (stall #1 — unavoidable) ----
    bf16x8 aA[4];
#pragma unroll
    for (int kt = 0; kt < 4; ++kt) {
#pragma unroll
      for (int j = 0; j < 8; ++j) {
        float p = (float)S[kt][j] * (float)D[kt][j];
        aA[kt][j] = (__bf16)fmaxf(p, 0.f);
      }
    }

    // ---- loads B into the SAME S/D regs (land under MFMA+epi A) ----
#pragma unroll
    for (int kt = 0; kt < 4; ++kt) {
      const int k0 = kt * 32 + quad * 8;
      S[kt] = *reinterpret_cast<const bf16x8*>(xsB + k0);
      D[kt] = *reinterpret_cast<const bf16x8*>(xdB + k0);
    }

    // ---- MFMA + epilogue A ----
    {
      f32x4 acc[8] = {};
#pragma unroll
      for (int kt = 0; kt < 4; ++kt) {
        const int k0 = kt * 32 + quad * 8;
#pragma unroll
        for (int nt = 0; nt < 8; ++nt) {
          bf16x8 bfr = *reinterpret_cast<const bf16x8*>(&sW[(nt * 16 + m) * PITCH + k0]);
          acc[nt] = __builtin_amdgcn_mfma_f32_16x16x32_bf16(aA[kt], bfr, acc[nt], 0, 0, 0);
        }
      }
      float p[4] = {0.f, 0.f, 0.f, 0.f};
#pragma unroll
      for (int nt = 0; nt < 8; ++nt) {
        const int n = nt * 16 + m;
        const float b1n = sb1[n], w2n = sw2[n];
#pragma unroll
        for (int r = 0; r < 4; ++r) p[r] = fmaf(fmaxf(acc[nt][r] + b1n, 0.f), w2n, p[r]);
      }
#pragma unroll
      for (int off = 1; off < 16; off <<= 1)
#pragma unroll
        for (int r = 0; r < 4; ++r) p[r] += __shfl_xor(p[r], off, 64);
      if (m == 0) {
        float4 o;
        o.x = 1.f / (1.f + __expf(-(p[0] + b2v)));
        o.y = 1.f / (1.f + __expf(-(p[1] + b2v)));
        o.z = 1.f / (1.f + __expf(-(p[2] + b2v)));
        o.w = 1.f / (1.f + __expf(-(p[3] + b2v)));
        *reinterpret_cast<float4*>(out + tileA * 64 + wave * 16 + quad * 4) = o;
      }
    }

    // ---- convert B (loads landed during A's compute — little/no stall) ----
    bf16x8 aB[4];
#pragma unroll
    for (int kt = 0; kt < 4; ++kt) {
#pragma unroll
      for (int j = 0; j < 8; ++j) {
        float p = (float)S[kt][j] * (float)D[kt][j];
        aB[kt][j] = (__bf16)fmaxf(p, 0.f);
      }
    }

    // ---- MFMA + epilogue B ----
    {
      f32x4 acc[8] = {};
#pragma unroll
      for (int kt = 0; kt < 4; ++kt) {
        const int k0 = kt * 32 + quad * 8;
#pragma unroll
        for (int nt = 0; nt < 8; ++nt) {
          bf16x8 bfr = *reinterpret_cast<const bf16x8*>(&sW[(nt * 16 + m) * PITCH + k0]);
          acc[nt] = __builtin_amdgcn_mfma_f32_16x16x32_bf16(aB[kt], bfr, acc[nt], 0, 0, 0);
        }
      }
      float p[4] = {0.f, 0.f, 0.f, 0.f};
#pragma unroll
      for (int nt = 0; nt < 8; ++nt) {
        const int n = nt * 16 + m;
        const float b1n = sb1[n], w2n = sw2[n];
#pragma unroll
        for (int r = 0; r < 4; ++r) p[r] = fmaf(fmaxf(acc[nt][r] + b1n, 0.f), w2n, p[r]);
      }
#pragma unroll
      for (int off = 1; off < 16; off <<= 1)
#pragma unroll
        for (int r = 0; r < 4; ++r) p[r] += __shfl_xor(p[r], off, 64);
      if (m == 0) {
        float4 o;
        o.x = 1.f / (1.f + __expf(-(p[0] + b2v)));
        o.y = 1.f / (1.f + __expf(-(p[1] + b2v)));
        o.z = 1.f / (1.f + __expf(-(p[2] + b2v)));
        o.w = 1.f / (1.f + __expf(-(p[3] + b2v)));
        *reinterpret_cast<float4*>(out + (tileA + 1) * 64 + wave * 16 + quad * 4) = o;
      }
    }
  }
}

// fp32 fallback (ws too small for xb)
__global__ __launch_bounds__(TPB) void vgae_decode_fallback(
    const float* __restrict__ x,
    const float* __restrict__ W1,
    const float* __restrict__ b1,
    const float* __restrict__ W2,
    const float* __restrict__ b2,
    const int* __restrict__ eip,
    const int* __restrict__ ein,
    float* __restrict__ out,
    int E, int n_tiles)
{
  __shared__ __bf16 sW[HID * PITCH];
  __shared__ float  sb1[HID];
  __shared__ float  sw2[HID];
  for (int c = threadIdx.x; c < HID * (HID / 8); c += TPB) {
    int n = c >> 4, k0 = (c & 15) << 3;
    bf16x8 v;
#pragma unroll
    for (int j = 0; j < 8; ++j) v[j] = (__bf16)W1[(k0 + j) * HID + n];
    *reinterpret_cast<bf16x8*>(&sW[n * PITCH + k0]) = v;
  }
  if (threadIdx.x < HID) { sb1[threadIdx.x] = b1[threadIdx.x]; sw2[threadIdx.x] = W2[threadIdx.x]; }
  __syncthreads();
  const int lane = threadIdx.x & 63, wave = threadIdx.x >> 6;
  const int m = lane & 15, quad = lane >> 4;
  const float b2v = b2[0];
  for (int tile = blockIdx.x; tile < n_tiles; tile += gridDim.x) {
    const int e_base = tile * 64 + wave * 16;
    const int* ei = (e_base < E) ? eip : ein;
    const int  eo = (e_base < E) ? e_base : (e_base - E);
    const int src = ei[eo + m], dst = ei[E + eo + m];
    const float* xs = x + (size_t)src * HID;
    const float* xd = x + (size_t)dst * HID;
    f32x4 acc[8] = {};
#pragma unroll
    for (int kt = 0; kt < 4; ++kt) {
      const int k0 = kt * 32 + quad * 8;
      float4 s0 = *reinterpret_cast<const float4*>(xs + k0);
      float4 s1 = *reinterpret_cast<const float4*>(xs + k0 + 4);
      float4 d0 = *reinterpret_cast<const float4*>(xd + k0);
      float4 d1 = *reinterpret_cast<const float4*>(xd + k0 + 4);
      bf16x8 a;
      a[0] = (__bf16)fmaxf(s0.x * d0.x, 0.f); a[1] = (__bf16)fmaxf(s0.y * d0.y, 0.f);
      a[2] = (__bf16)fmaxf(s0.z * d0.z, 0.f); a[3] = (__bf16)fmaxf(s0.w * d0.w, 0.f);
      a[4] = (__bf16)fmaxf(s1.x * d1.x, 0.f); a[5] = (__bf16)fmaxf(s1.y * d1.y, 0.f);
      a[6] = (__bf16)fmaxf(s1.z * d1.z, 0.f); a[7] = (__bf16)fmaxf(s1.w * d1.w, 0.f);
#pragma unroll
      for (int nt = 0; nt < 8; ++nt) {
        bf16x8 bfr = *reinterpret_cast<const bf16x8*>(&sW[(nt * 16 + m) * PITCH + k0]);
        acc[nt] = __builtin_amdgcn_mfma_f32_16x16x32_bf16(a, bfr, acc[nt], 0, 0, 0);
      }
    }
    float p[4] = {0.f, 0.f, 0.f, 0.f};
#pragma unroll
    for (int nt = 0; nt < 8; ++nt) {
      const int n = nt * 16 + m;
      const float b1n = sb1[n], w2n = sw2[n];
#pragma unroll
      for (int r = 0; r < 4; ++r) p[r] = fmaf(fmaxf(acc[nt][r] + b1n, 0.f), w2n, p[r]);
    }
#pragma unroll
    for (int off = 1; off < 16; off <<= 1)
#pragma unroll
      for (int r = 0; r < 4; ++r) p[r] += __shfl_xor(p[r], off, 64);
    if (m == 0) {
      float4 o;
      o.x = 1.f / (1.f + __expf(-(p[0] + b2v)));
      o.y = 1.f / (1.f + __expf(-(p[1] + b2v)));
      o.z = 1.f / (1.f + __expf(-(p[2] + b2v)));
      o.w = 1.f / (1.f + __expf(-(p[3] + b2v)));
      *reinterpret_cast<float4*>(out + tile * 64 + wave * 16 + quad * 4) = o;
    }
  }
}

extern "C" void kernel_launch(void* const* d_in, const int* in_sizes, int n_in,
                              void* d_out, int out_size, void* d_ws, size_t ws_size,
                              hipStream_t stream) {
  const float* x  = (const float*)d_in[0];
  const float* W1 = (const float*)d_in[1];
  const float* b1 = (const float*)d_in[2];
  const float* W2 = (const float*)d_in[3];
  const float* b2 = (const float*)d_in[4];
  const int*  eip = (const int*)d_in[5];
  const int*  ein = (const int*)d_in[6];
  float* out = (float*)d_out;
  const int E = in_sizes[5] / 2;
  const int n_tiles = (2 * E) / 64;
  const int n_nodes = in_sizes[0] / HID;
  const int n_x4 = in_sizes[0] / 4;

  const size_t w1t_bytes = (size_t)HID * PITCH * sizeof(__bf16);
  const size_t xb_off    = 65536;
  const size_t xb_bytes  = (size_t)n_nodes * HID * sizeof(__bf16);

  __bf16* w1t = nullptr;
  __bf16* xb  = nullptr;
  if (ws_size >= w1t_bytes) w1t = (__bf16*)d_ws;
  if (ws_size >= xb_off + xb_bytes) xb = (__bf16*)((char*)d_ws + xb_off);

  // pairwise kernel requires even n_tiles (E % 64 == 0); else use fallback
  if (w1t && xb && (n_tiles % 2 == 0)) {
    int prep_grid = (n_x4 + TPB - 1) / TPB;
    if (prep_grid > 6400) prep_grid = 6400;
    prep_kernel<<<prep_grid, TPB, 0, stream>>>(W1, w1t, x, xb, n_x4);
    // n_pairs = 10000; grid 2500 -> exactly 4 pairs (8 tiles) per block
    int n_pairs = n_tiles / 2;
    int grid = 2500;
    if (grid > n_pairs) grid = n_pairs;
    vgae_decode_kernel<<<grid, TPB, 0, stream>>>(xb, w1t, b1, W2, b2,
                                                 eip, ein, out, E, n_tiles);
  } else {
    vgae_decode_fallback<<<2560, TPB, 0, stream>>>(x, W1, b1, W2, b2,
                                                   eip, ein, out, E, n_tiles);
  }
}